// Round 5
// baseline (719.229 us; speedup 1.0000x reference)
//
#include <hip/hip_runtime.h>
#include <math.h>

// Problem constants (from reference)
#define HH 256
#define WW 256
#define CC 32
#define SS 32
#define NRAYS 32768            // N*R = 2*16384
#define RPB 8                  // rays per block
#define NWTS 4257
#define TEXOFF 256             // byte offset of HWC texture in d_ws

// LDS pool layout (bf16 MFMA body)
#define FXB_OFF 0              // fx/rgb rows: 256 x stride 40 bf16 (80 B); sigma f32 at +64
#define U_OFF   20480          // union: addrw 256x12x8 B (=24576)  |  hB 4 waves x 2304 B
#define W1T_OFF 45056          // W1^T [64][32] bf16 (4096 B)
#define W2T_OFF 49152          // W2^T [48][64] bf16 (6144 B)
#define B1S_OFF 55296          // b1 f32[64]
#define B2S_OFF 55552          // b2 f32[48] (pad 0)
#define POOLSZ  55808

typedef __attribute__((ext_vector_type(8))) short short8;   // 8 bf16 (4 VGPRs)
typedef __attribute__((ext_vector_type(4))) float f32x4;

__device__ __forceinline__ f32x4 mfma16(short8 a, short8 b, f32x4 c) {
    return __builtin_amdgcn_mfma_f32_16x16x32_bf16(a, b, c, 0, 0, 0);
}

// ---------- helpers ----------
__device__ __forceinline__ float bf2f(unsigned short u) {
    union { unsigned int ui; float f; } v; v.ui = ((unsigned int)u) << 16; return v.f;
}
__device__ __forceinline__ unsigned short f2bf(float f) {
    union { float f; unsigned int u; } v; v.f = f;
    unsigned int u = v.u;
    unsigned int r = u + 0x7fffu + ((u >> 16) & 1u);   // RNE
    return (unsigned short)(r >> 16);
}
__device__ __forceinline__ int iclamp(int x, int lo, int hi) {
    return x < lo ? lo : (x > hi ? hi : x);
}
__device__ __forceinline__ float softplus_f(float z) {
    return fmaxf(z, 0.f) + log1pf(expf(-fabsf(z)));
}

template<bool F32>
__device__ __forceinline__ float ldv(const void* p, size_t i) {
    if (F32) return ((const float*)p)[i];
    else     return bf2f(((const unsigned short*)p)[i]);
}

// ---------- dtype detection: |ray_origin| == 2.7 (by construction) ----------
__global__ void detect_dtype(const void* __restrict__ rayo, int* __restrict__ flag) {
    if (threadIdx.x == 0 && blockIdx.x == 0) {
        const float* f = (const float*)rayo;
        const unsigned short* u = (const unsigned short*)rayo;
        float sf = 0.f, sb = 0.f;
        for (int r = 0; r < 8; r++) {
            const float a = f[3 * r], b = f[3 * r + 1], c = f[3 * r + 2];
            const float nf = a * a + b * b + c * c;
            sf += fminf(fabsf(nf - 7.29f), 1e3f);
            const float x = bf2f(u[3 * r]), y = bf2f(u[3 * r + 1]), z = bf2f(u[3 * r + 2]);
            const float nb = x * x + y * y + z * z;
            sb += fminf(fabsf(nb - 7.29f), 1e3f);
        }
        *flag = (sf < sb) ? 1 : 0;   // 1 = float32 inputs
    }
}

// ---------- CHW -> HWC transpose of the 6 planes ----------
__global__ __launch_bounds__(1024) void transpose_tex(
    const void* __restrict__ vol, void* __restrict__ tex, const int* __restrict__ flag) {
    __shared__ float          tf[32][33];
    __shared__ unsigned short tu[32][33];
    const int tx = threadIdx.x, ty = threadIdx.y;
    const int w0 = blockIdx.x * 32;
    const int h  = blockIdx.y;
    const int img = blockIdx.z;
    const size_t src = (((size_t)img * CC + ty) * HH + h) * WW + (w0 + tx);
    const size_t dst = (((size_t)img * HH + h) * WW + (w0 + ty)) * CC + tx;
    if (*flag) {
        tf[ty][tx] = ((const float*)vol)[src];
        __syncthreads();
        ((float*)tex)[dst] = tf[tx][ty];
    } else {
        tu[ty][tx] = ((const unsigned short*)vol)[src];
        __syncthreads();
        ((unsigned short*)tex)[dst] = tu[tx][ty];
    }
}

// ================= f32 fallback body (round-4 verified) =================
__device__ void render_f32_body(
    const void* __restrict__ tex, const void* __restrict__ rayo,
    const void* __restrict__ rayd, const void* __restrict__ w1b,
    const void* __restrict__ b1b, const void* __restrict__ w2b,
    const void* __restrict__ b2b, void* __restrict__ outp,
    float* __restrict__ wsm, float* __restrict__ fxb, float* __restrict__ sigL)
{
    const int t = threadIdx.x;
    for (int i = t; i < NWTS; i += 256) {
        float v;
        if (i < 2048)       v = ldv<true>(w1b, i);
        else if (i < 2112)  v = ldv<true>(b1b, i - 2048);
        else if (i < 4224)  v = ldv<true>(w2b, i - 2112);
        else                v = ldv<true>(b2b, i - 4224);
        wsm[i] = v;
    }
    {
        const int c = t & 31;
        const int g = t >> 5;
        const int gray = blockIdx.x * RPB + g;
        const int n = gray >> 14;
        const size_t rbase = (size_t)gray * 3;
        const float ox = ldv<true>(rayo, rbase), oy = ldv<true>(rayo, rbase + 1), oz = ldv<true>(rayo, rbase + 2);
        const float dx = ldv<true>(rayd, rbase), dy = ldv<true>(rayd, rbase + 1), dz = ldv<true>(rayd, rbase + 2);
        #pragma unroll 1
        for (int s = 0; s < 32; ++s) {
            const float d = 2.25f + 1.05f * ((s + 0.5f) * (1.0f / 32.0f));
            const float x = (ox + d * dx) * 2.0f;
            const float y = (oy + d * dy) * 2.0f;
            const float z = (oz + d * dz) * 2.0f;
            float acc = 0.f;
            #pragma unroll
            for (int p = 0; p < 3; p++) {
                const float u = (p == 0) ? x : ((p == 1) ? y : x);
                const float v = (p == 0) ? y : z;
                const float ixf = fmaf(u, 127.5f, 127.5f);
                const float iyf = fmaf(v, 127.5f, 127.5f);
                const float ix0f = floorf(ixf), iy0f = floorf(iyf);
                const float wx1 = ixf - ix0f, wy1 = iyf - iy0f;
                const float wx0 = 1.f - wx1,  wy0 = 1.f - wy1;
                const int ix0 = iclamp((int)ix0f, 0, 255);
                const int ix1 = iclamp((int)ix0f + 1, 0, 255);
                const int iy0 = iclamp((int)iy0f, 0, 255);
                const int iy1 = iclamp((int)iy0f + 1, 0, 255);
                const float wnw = wx0 * wy0, wne = wx1 * wy0, wsw = wx0 * wy1, wse = wx1 * wy1;
                const size_t pb = (size_t)(n * 3 + p) * HH * WW * CC;
                acc += wnw * ldv<true>(tex, pb + ((size_t)iy0 * WW + ix0) * CC + c)
                     + wne * ldv<true>(tex, pb + ((size_t)iy0 * WW + ix1) * CC + c)
                     + wsw * ldv<true>(tex, pb + ((size_t)iy1 * WW + ix0) * CC + c)
                     + wse * ldv<true>(tex, pb + ((size_t)iy1 * WW + ix1) * CC + c);
            }
            fxb[(g * 32 + s) * 33 + c] = acc * (1.0f / 3.0f);
        }
    }
    __syncthreads();

    const int rl = t >> 5;
    const int gray = blockIdx.x * RPB + rl;
    float fx[32];
    #pragma unroll
    for (int c = 0; c < 32; c++) fx[c] = fxb[t * 33 + c];

    const float* W1 = wsm;
    const float* B1 = wsm + 2048;
    const float* W2 = wsm + 2112;
    const float* B2 = wsm + 4224;

    float h[64];
    #pragma unroll
    for (int j = 0; j < 64; j++) h[j] = B1[j];
    #pragma unroll
    for (int c = 0; c < 32; c++) {
        const float f = fx[c];
        #pragma unroll
        for (int j = 0; j < 64; j++) h[j] = fmaf(f, W1[c * 64 + j], h[j]);
    }
    #pragma unroll
    for (int j = 0; j < 64; j++) h[j] = softplus_f(h[j]);

    #pragma unroll 1
    for (int k = 0; k < 33; k++) {
        float zz = B2[k];
        #pragma unroll
        for (int j = 0; j < 64; j++) zz = fmaf(h[j], W2[j * 33 + k], zz);
        if (k == 0) {
            sigL[t] = zz;
        } else {
            const float sg = 1.0f / (1.0f + expf(-zz));
            fxb[t * 33 + (k - 1)] = fmaf(sg, 1.002f, -0.001f);
        }
    }
    __syncthreads();

    const int c = t & 31;
    const float delta = 1.05f / 32.0f;
    float T = 1.0f, acc = 0.0f;
    float sig_prev = sigL[rl * 32 + 0];
    float rgb_prev = fxb[(rl * 32 + 0) * 33 + c];
    #pragma unroll 1
    for (int sm = 0; sm < 31; sm++) {
        const float sig_next = sigL[rl * 32 + sm + 1];
        const float rgb_next = fxb[(rl * 32 + sm + 1) * 33 + c];
        const float dm = 0.5f * (sig_prev + sig_next) - 1.0f;
        const float dens = softplus_f(dm);
        const float alpha = 1.0f - expf(-delta * dens);
        acc += alpha * T * 0.5f * (rgb_prev + rgb_next);
        T *= (1.0f - alpha + 1e-10f);
        sig_prev = sig_next;
        rgb_prev = rgb_next;
    }
    ((float*)outp)[(size_t)gray * 32 + c] = acc;
}

// ================= bf16 MFMA fast path =================
__global__ __launch_bounds__(256) void render_fast(
    const void* __restrict__ tex, const void* __restrict__ rayo,
    const void* __restrict__ rayd, const void* __restrict__ w1b,
    const void* __restrict__ b1b, const void* __restrict__ w2b,
    const void* __restrict__ b2b, void* __restrict__ outp,
    const int* __restrict__ flag)
{
    __shared__ __align__(16) char pool[POOLSZ];

    if (*flag) {   // f32 inputs: verified round-4 path
        render_f32_body(tex, rayo, rayd, w1b, b1b, w2b, b2b, outp,
                        (float*)pool, (float*)(pool + 17056), (float*)(pool + 50848));
        return;
    }

    const int t = threadIdx.x;
    const unsigned short* ro  = (const unsigned short*)rayo;
    const unsigned short* rd  = (const unsigned short*)rayd;
    const unsigned short* w1u = (const unsigned short*)w1b;
    const unsigned short* b1u = (const unsigned short*)b1b;
    const unsigned short* w2u = (const unsigned short*)w2b;
    const unsigned short* b2u = (const unsigned short*)b2b;

    unsigned short* fxB = (unsigned short*)pool;              // stride 40 bf16 / row
    uint2*  aw  = (uint2*)(pool + U_OFF);                     // 12 (addr,wgt) pairs / sample
    unsigned short* w1t = (unsigned short*)(pool + W1T_OFF);  // [n<64][k<32]
    unsigned short* w2t = (unsigned short*)(pool + W2T_OFF);  // [n<48][k<64]
    float* b1s = (float*)(pool + B1S_OFF);
    float* b2s = (float*)(pool + B2S_OFF);

    // ---- stage weights (bf16 kept native; transposed to B-frag layout) ----
    for (int i = t; i < 2048; i += 256) { const int k = i >> 6, n = i & 63; w1t[n * 32 + k] = w1u[i]; }
    for (int i = t; i < 3072; i += 256) {
        const int n = i >> 6, k = i & 63;
        w2t[n * 64 + k] = (n < 33) ? w2u[k * 33 + n] : (unsigned short)0;
    }
    if (t < 64) b1s[t] = bf2f(b1u[t]);
    if (t < 48) b2s[t] = (t < 33) ? bf2f(b2u[t]) : 0.f;

    // ---- phase A: thread t owns sample t -> 12 (addr, wgt) pairs ----
    {
        const int rt = t >> 5, s = t & 31;
        const int gray = blockIdx.x * RPB + rt;
        const int n = gray >> 14;
        const size_t rb = (size_t)gray * 3;
        const float ox = bf2f(ro[rb]), oy = bf2f(ro[rb + 1]), oz = bf2f(ro[rb + 2]);
        const float dx = bf2f(rd[rb]), dy = bf2f(rd[rb + 1]), dz = bf2f(rd[rb + 2]);
        const float d = 2.25f + 1.05f * ((s + 0.5f) * (1.0f / 32.0f));
        const float x = (ox + d * dx) * 2.0f;
        const float y = (oy + d * dy) * 2.0f;
        const float z = (oz + d * dz) * 2.0f;
        uint2* row = aw + t * 12;
        #pragma unroll
        for (int p = 0; p < 3; p++) {
            const float u = (p == 0) ? x : ((p == 1) ? y : x);
            const float v = (p == 0) ? y : z;
            const float ixf = fmaf(u, 127.5f, 127.5f);
            const float iyf = fmaf(v, 127.5f, 127.5f);
            const float ix0f = floorf(ixf), iy0f = floorf(iyf);
            const float wx1 = ixf - ix0f, wy1 = iyf - iy0f;
            const float wx0 = 1.f - wx1,  wy0 = 1.f - wy1;
            const int ix0 = iclamp((int)ix0f, 0, 255);
            const int ix1 = iclamp((int)ix0f + 1, 0, 255);
            const int iy0 = iclamp((int)iy0f, 0, 255);
            const int iy1 = iclamp((int)iy0f + 1, 0, 255);
            const unsigned int pb = (unsigned int)(n * 3 + p) * (HH * WW * CC * 2);
            uint2 q;
            q.x = pb + ((unsigned int)(iy0 * WW + ix0) << 6); q.y = __float_as_uint(wx0 * wy0); row[p * 4 + 0] = q;
            q.x = pb + ((unsigned int)(iy0 * WW + ix1) << 6); q.y = __float_as_uint(wx1 * wy0); row[p * 4 + 1] = q;
            q.x = pb + ((unsigned int)(iy1 * WW + ix0) << 6); q.y = __float_as_uint(wx0 * wy1); row[p * 4 + 2] = q;
            q.x = pb + ((unsigned int)(iy1 * WW + ix1) << 6); q.y = __float_as_uint(wx1 * wy1); row[p * 4 + 3] = q;
        }
    }
    __syncthreads();

    // ---- phase B: group g (32 lanes) fetch+blend ray g, lane = channel ----
    {
        const int g = t >> 5, c = t & 31;
        const int coff = c << 1;
        const char* texb = (const char*)tex;
        #pragma unroll 2
        for (int s = 0; s < 32; ++s) {
            const int rowi = g * 32 + s;
            const uint4* q = (const uint4*)(pool + U_OFF + rowi * 96);
            float acc = 0.f;
            #pragma unroll
            for (int h = 0; h < 6; h++) {
                const uint4 pr = q[h];
                const float va = bf2f(*(const unsigned short*)(texb + pr.x + coff));
                const float vb = bf2f(*(const unsigned short*)(texb + pr.z + coff));
                acc = fmaf(__uint_as_float(pr.y), va, acc);
                acc = fmaf(__uint_as_float(pr.w), vb, acc);
            }
            fxB[rowi * 40 + c] = f2bf(acc * (1.0f / 3.0f));
        }
    }
    __syncthreads();

    // ---- MFMA MLP: wave w owns samples [64w, 64w+64) ----
    {
        const int w = t >> 6;
        const int lane = t & 63;
        const int l16 = lane & 15, quad = lane >> 4;

        short8 b1f[4];
        #pragma unroll
        for (int nt = 0; nt < 4; nt++)
            b1f[nt] = *(const short8*)(pool + W1T_OFF + (nt * 16 + l16) * 64 + quad * 16);
        short8 b2f[3][2];
        #pragma unroll
        for (int nt = 0; nt < 3; nt++)
            #pragma unroll
            for (int ks = 0; ks < 2; ks++)
                b2f[nt][ks] = *(const short8*)(pool + W2T_OFF + (nt * 16 + l16) * 128 + ks * 64 + quad * 16);
        const float bb1[4] = { b1s[l16], b1s[16 + l16], b1s[32 + l16], b1s[48 + l16] };
        const float bb2[3] = { b2s[l16], b2s[16 + l16], b2s[32 + l16] };
        char* hb = pool + U_OFF + w * 2304;   // aliases addrw (dead after phase B)

        #pragma unroll 1
        for (int mt = 0; mt < 4; mt++) {
            const int rbase = w * 64 + mt * 16;
            const short8 a1 = *(const short8*)(pool + FXB_OFF + (size_t)(rbase + l16) * 80 + quad * 16);
            #pragma unroll
            for (int nt = 0; nt < 4; nt++) {
                f32x4 hc = { bb1[nt], bb1[nt], bb1[nt], bb1[nt] };
                hc = mfma16(a1, b1f[nt], hc);
                #pragma unroll
                for (int r = 0; r < 4; r++) {
                    const float hv = softplus_f(hc[r]);
                    *(unsigned short*)(hb + (quad * 4 + r) * 144 + (nt * 16 + l16) * 2) = f2bf(hv);
                }
            }
            const short8 a2k0 = *(const short8*)(hb + l16 * 144 + quad * 16);
            const short8 a2k1 = *(const short8*)(hb + l16 * 144 + 64 + quad * 16);
            #pragma unroll
            for (int nt = 0; nt < 3; nt++) {
                f32x4 o = { bb2[nt], bb2[nt], bb2[nt], bb2[nt] };
                o = mfma16(a2k0, b2f[nt][0], o);
                o = mfma16(a2k1, b2f[nt][1], o);
                #pragma unroll
                for (int r = 0; r < 4; r++) {
                    const int row = rbase + quad * 4 + r;
                    if (nt == 0) {
                        if (l16 == 0) {
                            *(float*)(pool + (size_t)row * 80 + 64) = o[r];   // raw sigma z (col 0)
                        } else {
                            const float sg = 1.0f / (1.0f + expf(-o[r]));
                            fxB[row * 40 + (l16 - 1)] = f2bf(fmaf(sg, 1.002f, -0.001f));  // rgb ch 0..14
                        }
                    } else if (nt == 1) {
                        const float sg = 1.0f / (1.0f + expf(-o[r]));
                        fxB[row * 40 + (15 + l16)] = f2bf(fmaf(sg, 1.002f, -0.001f));     // rgb ch 15..30
                    } else if (l16 == 0) {
                        const float sg = 1.0f / (1.0f + expf(-o[r]));
                        fxB[row * 40 + 31] = f2bf(fmaf(sg, 1.002f, -0.001f));             // rgb ch 31
                    }
                }
            }
        }
    }

    // ---- ray march (intra-wave: rows [64w,64w+64) written by this wave) ----
    {
        const int rl = t >> 5, c = t & 31;
        const int gray = blockIdx.x * RPB + rl;
        const float delta = 1.05f / 32.0f;
        float T = 1.0f, acc = 0.0f;
        int row = rl * 32;
        float sp = *(const float*)(pool + (size_t)row * 80 + 64);
        float rp = bf2f(fxB[row * 40 + c]);
        #pragma unroll 1
        for (int sm = 0; sm < 31; sm++) {
            row++;
            const float sn = *(const float*)(pool + (size_t)row * 80 + 64);
            const float rn = bf2f(fxB[row * 40 + c]);
            const float dens = softplus_f(0.5f * (sp + sn) - 1.0f);
            const float alpha = 1.0f - expf(-delta * dens);
            acc += alpha * T * 0.5f * (rp + rn);
            T *= (1.0f - alpha + 1e-10f);
            sp = sn; rp = rn;
        }
        ((unsigned short*)outp)[(size_t)gray * 32 + c] = f2bf(acc);
    }
}

// ================= no-workspace fallback (round-3 verified) =================
template<bool F32>
__device__ __forceinline__ void render_body(
    const void* __restrict__ vol, const void* __restrict__ rayo,
    const void* __restrict__ rayd, const void* __restrict__ w1b,
    const void* __restrict__ b1b, const void* __restrict__ w2b,
    const void* __restrict__ b2b, void* __restrict__ outp,
    float* wsm, float (*rgbL)[SS][33], float (*sigL)[SS])
{
    const int t = threadIdx.x;
    for (int i = t; i < NWTS; i += 256) {
        float v;
        if (i < 2048)       v = ldv<F32>(w1b, i);
        else if (i < 2112)  v = ldv<F32>(b1b, i - 2048);
        else if (i < 4224)  v = ldv<F32>(w2b, i - 2112);
        else                v = ldv<F32>(b2b, i - 4224);
        wsm[i] = v;
    }
    __syncthreads();

    const int rl = t >> 5;
    const int s  = t & 31;
    const int gray = blockIdx.x * RPB + rl;
    const int n = gray >> 14;

    const size_t rbase = (size_t)gray * 3;
    const float ox = ldv<F32>(rayo, rbase), oy = ldv<F32>(rayo, rbase + 1), oz = ldv<F32>(rayo, rbase + 2);
    const float dx = ldv<F32>(rayd, rbase), dy = ldv<F32>(rayd, rbase + 1), dz = ldv<F32>(rayd, rbase + 2);
    const float d = 2.25f + 1.05f * ((s + 0.5f) * (1.0f / 32.0f));
    const float x = (ox + d * dx) * 2.0f;
    const float y = (oy + d * dy) * 2.0f;
    const float z = (oz + d * dz) * 2.0f;

    float fx[32];
    #pragma unroll
    for (int c = 0; c < 32; c++) fx[c] = 0.f;

    #pragma unroll
    for (int p = 0; p < 3; p++) {
        const float u = (p == 0) ? x : ((p == 1) ? y : x);
        const float v = (p == 0) ? y : z;
        const float ixf = fmaf(u, 127.5f, 127.5f);
        const float iyf = fmaf(v, 127.5f, 127.5f);
        const float ix0f = floorf(ixf), iy0f = floorf(iyf);
        const float wx1 = ixf - ix0f, wy1 = iyf - iy0f;
        const float wx0 = 1.f - wx1,  wy0 = 1.f - wy1;
        const int ix0 = iclamp((int)ix0f, 0, 255);
        const int ix1 = iclamp((int)ix0f + 1, 0, 255);
        const int iy0 = iclamp((int)iy0f, 0, 255);
        const int iy1 = iclamp((int)iy0f + 1, 0, 255);
        const float wnw = wx0 * wy0, wne = wx1 * wy0, wsw = wx0 * wy1, wse = wx1 * wy1;
        const int i00 = iy0 * WW + ix0, i01 = iy0 * WW + ix1;
        const int i10 = iy1 * WW + ix0, i11 = iy1 * WW + ix1;
        const size_t pb = (size_t)(n * 3 + p) * CC * HH * WW;
        #pragma unroll
        for (int c = 0; c < 32; c++) {
            const size_t cb = pb + (size_t)c * (HH * WW);
            fx[c] += wnw * ldv<F32>(vol, cb + i00) + wne * ldv<F32>(vol, cb + i01)
                   + wsw * ldv<F32>(vol, cb + i10) + wse * ldv<F32>(vol, cb + i11);
        }
    }
    #pragma unroll
    for (int c = 0; c < 32; c++) fx[c] *= (1.0f / 3.0f);

    const float* W1 = wsm;
    const float* B1 = wsm + 2048;
    const float* W2 = wsm + 2112;
    const float* B2 = wsm + 4224;

    float h[64];
    #pragma unroll
    for (int j = 0; j < 64; j++) h[j] = B1[j];
    #pragma unroll
    for (int c = 0; c < 32; c++) {
        const float f = fx[c];
        #pragma unroll
        for (int j = 0; j < 64; j++) h[j] = fmaf(f, W1[c * 64 + j], h[j]);
    }
    #pragma unroll
    for (int j = 0; j < 64; j++) h[j] = softplus_f(h[j]);

    #pragma unroll 1
    for (int k = 0; k < 33; k++) {
        float zz = B2[k];
        #pragma unroll
        for (int j = 0; j < 64; j++) zz = fmaf(h[j], W2[j * 33 + k], zz);
        if (k == 0) sigL[rl][s] = zz;
        else {
            const float sg = 1.0f / (1.0f + expf(-zz));
            rgbL[rl][s][k - 1] = fmaf(sg, 1.002f, -0.001f);
        }
    }
    __syncthreads();

    const int c = t & 31;
    const float delta = 1.05f / 32.0f;
    float T = 1.0f, acc = 0.0f;
    float sig_prev = sigL[rl][0];
    float rgb_prev = rgbL[rl][0][c];
    #pragma unroll 1
    for (int sm = 0; sm < 31; sm++) {
        const float sig_next = sigL[rl][sm + 1];
        const float rgb_next = rgbL[rl][sm + 1][c];
        const float dens = softplus_f(0.5f * (sig_prev + sig_next) - 1.0f);
        const float alpha = 1.0f - expf(-delta * dens);
        acc += alpha * T * 0.5f * (rgb_prev + rgb_next);
        T *= (1.0f - alpha + 1e-10f);
        sig_prev = sig_next;
        rgb_prev = rgb_next;
    }
    const size_t oidx = (size_t)gray * 32 + c;
    if (F32) ((float*)outp)[oidx] = acc;
    else     ((unsigned short*)outp)[oidx] = f2bf(acc);
}

__global__ __launch_bounds__(256) void render_any(
    const void* __restrict__ vol, const void* __restrict__ rayo,
    const void* __restrict__ rayd, const void* __restrict__ w1b,
    const void* __restrict__ b1b, const void* __restrict__ w2b,
    const void* __restrict__ b2b, void* __restrict__ outp,
    const int* __restrict__ flag)
{
    __shared__ float wsm[NWTS];
    __shared__ float rgbL[RPB][SS][33];
    __shared__ float sigL[RPB][SS];
    if (*flag) render_body<true >(vol, rayo, rayd, w1b, b1b, w2b, b2b, outp, wsm, rgbL, sigL);
    else       render_body<false>(vol, rayo, rayd, w1b, b1b, w2b, b2b, outp, wsm, rgbL, sigL);
}

extern "C" void kernel_launch(void* const* d_in, const int* in_sizes, int n_in,
                              void* d_out, int out_size, void* d_ws, size_t ws_size,
                              hipStream_t stream) {
    const void* vol  = d_in[0];
    const void* rayo = d_in[1];
    const void* rayd = d_in[2];
    const void* w1   = d_in[3];
    const void* b1   = d_in[4];
    const void* w2   = d_in[5];
    const void* b2   = d_in[6];
    int* flag = (int*)d_ws;
    void* tex = (void*)((char*)d_ws + TEXOFF);

    const size_t need = TEXOFF + (size_t)6 * HH * WW * CC * 4;   // f32 worst case

    detect_dtype<<<dim3(1), dim3(64), 0, stream>>>(rayo, flag);
    if (ws_size >= need) {
        transpose_tex<<<dim3(WW / 32, HH, 6), dim3(32, 32), 0, stream>>>(vol, tex, flag);
        render_fast<<<dim3(NRAYS / RPB), dim3(256), 0, stream>>>(
            tex, rayo, rayd, w1, b1, w2, b2, d_out, flag);
    } else {
        render_any<<<dim3(NRAYS / RPB), dim3(256), 0, stream>>>(
            vol, rayo, rayd, w1, b1, w2, b2, d_out, flag);
    }
}

// Round 6
// 617.835 us; speedup vs baseline: 1.1641x; 1.1641x over previous
//
#include <hip/hip_runtime.h>
#include <math.h>

// Problem constants (from reference)
#define HH 256
#define WW 256
#define CC 32
#define SS 32
#define NRAYS 32768            // N*R = 2*16384
#define RPB 8                  // rays per block
#define TEXOFF 256             // byte offset of HWC texture in d_ws
#define FSTRIDE 36             // f32 elements per fx/rgb row (pad vs 33; 144 B, 16-aligned)

// ---------- helpers ----------
__device__ __forceinline__ float bf2f(unsigned short u) {
    union { unsigned int ui; float f; } v; v.ui = ((unsigned int)u) << 16; return v.f;
}
__device__ __forceinline__ unsigned short f2bf(float f) {
    union { float f; unsigned int u; } v; v.f = f;
    unsigned int u = v.u;
    unsigned int r = u + 0x7fffu + ((u >> 16) & 1u);   // RNE
    return (unsigned short)(r >> 16);
}
__device__ __forceinline__ int iclamp(int x, int lo, int hi) {
    return x < lo ? lo : (x > hi ? hi : x);
}
__device__ __forceinline__ float softplus_f(float z) {
    return fmaxf(z, 0.f) + log1pf(expf(-fabsf(z)));
}

template<bool F32>
__device__ __forceinline__ float ldv(const void* p, size_t i) {
    if (F32) return ((const float*)p)[i];
    else     return bf2f(((const unsigned short*)p)[i]);
}

// ---------- dtype detection: |ray_origin| == 2.7 (by construction) ----------
__global__ void detect_dtype(const void* __restrict__ rayo, int* __restrict__ flag) {
    if (threadIdx.x == 0 && blockIdx.x == 0) {
        const float* f = (const float*)rayo;
        const unsigned short* u = (const unsigned short*)rayo;
        float sf = 0.f, sb = 0.f;
        for (int r = 0; r < 8; r++) {
            const float a = f[3 * r], b = f[3 * r + 1], c = f[3 * r + 2];
            const float nf = a * a + b * b + c * c;
            sf += fminf(fabsf(nf - 7.29f), 1e3f);       // fminf(NaN,x)=x -> NaN-safe
            const float x = bf2f(u[3 * r]), y = bf2f(u[3 * r + 1]), z = bf2f(u[3 * r + 2]);
            const float nb = x * x + y * y + z * z;
            sb += fminf(fabsf(nb - 7.29f), 1e3f);
        }
        *flag = (sf < sb) ? 1 : 0;   // 1 = float32 inputs
    }
}

// ---------- CHW -> HWC transpose of the 6 planes ----------
__global__ __launch_bounds__(1024) void transpose_tex(
    const void* __restrict__ vol, void* __restrict__ tex, const int* __restrict__ flag) {
    __shared__ float          tf[32][33];
    __shared__ unsigned short tu[32][33];
    const int tx = threadIdx.x, ty = threadIdx.y;
    const int w0 = blockIdx.x * 32;
    const int h  = blockIdx.y;
    const int img = blockIdx.z;
    const size_t src = (((size_t)img * CC + ty) * HH + h) * WW + (w0 + tx);
    const size_t dst = (((size_t)img * HH + h) * WW + (w0 + ty)) * CC + tx;
    if (*flag) {
        tf[ty][tx] = ((const float*)vol)[src];
        __syncthreads();
        ((float*)tex)[dst] = tf[tx][ty];
    } else {
        tu[ty][tx] = ((const unsigned short*)vol)[src];
        __syncthreads();
        ((unsigned short*)tex)[dst] = tu[tx][ty];
    }
}

// ================= optimized body: HWC gather + SGPR-weight MLP =================
// Key point: all weight/bias reads use wave-uniform indices on kernel-arg
// pointers -> compiler emits s_load (SMEM, K$-cached), zero LDS traffic.
template<bool F32>
__device__ void render_opt_body(
    const void* __restrict__ tex,   // [6][256][256][32] HWC
    const void* __restrict__ rayo, const void* __restrict__ rayd,
    const void* __restrict__ w1b, const void* __restrict__ b1b,
    const void* __restrict__ w2b, const void* __restrict__ b2b,
    void* __restrict__ outp,
    float* __restrict__ fxB,        // [256 * FSTRIDE] fx rows; reused as rgb rows
    float* __restrict__ sigL)       // [256]
{
    const int t = threadIdx.x;
    const int g = t >> 5, c = t & 31;          // gather: group g = ray, lane = channel
    const int gray = blockIdx.x * RPB + g;
    const int n = gray >> 14;

    // ---- gather: lane-cooperative, one coalesced load per corner ----
    {
        const size_t rb = (size_t)gray * 3;
        const float ox = ldv<F32>(rayo, rb), oy = ldv<F32>(rayo, rb + 1), oz = ldv<F32>(rayo, rb + 2);
        const float dx = ldv<F32>(rayd, rb), dy = ldv<F32>(rayd, rb + 1), dz = ldv<F32>(rayd, rb + 2);
        #pragma unroll 2
        for (int s = 0; s < 32; ++s) {
            const float d = 2.25f + 1.05f * ((s + 0.5f) * (1.0f / 32.0f));
            const float x = (ox + d * dx) * 2.0f;
            const float y = (oy + d * dy) * 2.0f;
            const float z = (oz + d * dz) * 2.0f;
            float a0 = 0.f, a1 = 0.f, a2 = 0.f;
            #pragma unroll
            for (int p = 0; p < 3; p++) {
                // p0:(x,y)  p1:(y,z)  p2:(x,z)
                const float u = (p == 0) ? x : ((p == 1) ? y : x);
                const float v = (p == 0) ? y : z;
                const float ixf = fmaf(u, 127.5f, 127.5f);
                const float iyf = fmaf(v, 127.5f, 127.5f);
                const float ix0f = floorf(ixf), iy0f = floorf(iyf);
                const float wx1 = ixf - ix0f, wy1 = iyf - iy0f;
                const float wx0 = 1.f - wx1,  wy0 = 1.f - wy1;
                const int ix0 = iclamp((int)ix0f, 0, 255);
                const int ix1 = iclamp((int)ix0f + 1, 0, 255);
                const int iy0 = iclamp((int)iy0f, 0, 255);
                const int iy1 = iclamp((int)iy0f + 1, 0, 255);
                const unsigned int pb = (unsigned int)(n * 3 + p) * (HH * WW * CC);
                const float v00 = ldv<F32>(tex, pb + ((unsigned int)(iy0 * WW + ix0) << 5) + c);
                const float v01 = ldv<F32>(tex, pb + ((unsigned int)(iy0 * WW + ix1) << 5) + c);
                const float v10 = ldv<F32>(tex, pb + ((unsigned int)(iy1 * WW + ix0) << 5) + c);
                const float v11 = ldv<F32>(tex, pb + ((unsigned int)(iy1 * WW + ix1) << 5) + c);
                float acc;
                acc = (wx0 * wy0) * v00;
                acc = fmaf(wx1 * wy0, v01, acc);
                acc = fmaf(wx0 * wy1, v10, acc);
                acc = fmaf(wx1 * wy1, v11, acc);
                if (p == 0) a0 = acc; else if (p == 1) a1 = acc; else a2 = acc;
            }
            fxB[(g * 32 + s) * FSTRIDE + c] = (a0 + a1 + a2) * (1.0f / 3.0f);
        }
    }
    __syncthreads();

    // ---- MLP: thread t owns sample row t; weights via uniform (scalar) loads ----
    {
        float h[64];
        #pragma unroll
        for (int j = 0; j < 64; j++) h[j] = ldv<F32>(b1b, j);
        #pragma unroll 1
        for (int c2 = 0; c2 < 32; c2++) {
            const float f = fxB[t * FSTRIDE + c2];
            #pragma unroll
            for (int j = 0; j < 64; j++) h[j] = fmaf(f, ldv<F32>(w1b, c2 * 64 + j), h[j]);
        }
        #pragma unroll
        for (int j = 0; j < 64; j++) h[j] = softplus_f(h[j]);

        float zv[33];
        #pragma unroll
        for (int k = 0; k < 33; k++) zv[k] = ldv<F32>(b2b, k);
        #pragma unroll 1
        for (int j = 0; j < 64; j++) {
            const float hv = h[j];
            #pragma unroll
            for (int k = 0; k < 33; k++) zv[k] = fmaf(hv, ldv<F32>(w2b, j * 33 + k), zv[k]);
        }

        sigL[t] = zv[0];                              // raw sigma
        #pragma unroll
        for (int k = 1; k < 33; k++) {
            const float sg = 1.0f / (1.0f + expf(-zv[k]));
            fxB[t * FSTRIDE + (k - 1)] = fmaf(sg, 1.002f, -0.001f);   // rgb (row t: own thread)
        }
    }
    __syncthreads();

    // ---- ray march: thread (rl, c) walks samples of ray rl ----
    {
        const int rl = t >> 5;
        const int gr2 = blockIdx.x * RPB + rl;
        const float delta = 1.05f / 32.0f;
        float T = 1.0f, acc = 0.0f;
        float sp = sigL[rl * 32 + 0];
        float rp = fxB[(rl * 32 + 0) * FSTRIDE + c];
        #pragma unroll 1
        for (int sm = 0; sm < 31; sm++) {
            const float sn = sigL[rl * 32 + sm + 1];
            const float rn = fxB[(rl * 32 + sm + 1) * FSTRIDE + c];
            const float dens = softplus_f(0.5f * (sp + sn) - 1.0f);
            const float alpha = 1.0f - expf(-delta * dens);
            acc += alpha * T * 0.5f * (rp + rn);
            T *= (1.0f - alpha + 1e-10f);
            sp = sn; rp = rn;
        }
        const size_t oidx = (size_t)gr2 * 32 + c;
        if (F32) ((float*)outp)[oidx] = acc;
        else     ((unsigned short*)outp)[oidx] = f2bf(acc);
    }
}

__global__ __launch_bounds__(256, 4) void render_fast(
    const void* __restrict__ tex, const void* __restrict__ rayo,
    const void* __restrict__ rayd, const void* __restrict__ w1b,
    const void* __restrict__ b1b, const void* __restrict__ w2b,
    const void* __restrict__ b2b, void* __restrict__ outp,
    const int* __restrict__ flag)
{
    __shared__ float fxB[256 * FSTRIDE];   // 36864 B
    __shared__ float sigL[256];            // 1024 B  -> ~38 KB total: 4 blocks/CU
    if (*flag) render_opt_body<true >(tex, rayo, rayd, w1b, b1b, w2b, b2b, outp, fxB, sigL);
    else       render_opt_body<false>(tex, rayo, rayd, w1b, b1b, w2b, b2b, outp, fxB, sigL);
}

// ================= no-workspace fallback (round-3 verified) =================
template<bool F32>
__device__ __forceinline__ void render_body(
    const void* __restrict__ vol, const void* __restrict__ rayo,
    const void* __restrict__ rayd, const void* __restrict__ w1b,
    const void* __restrict__ b1b, const void* __restrict__ w2b,
    const void* __restrict__ b2b, void* __restrict__ outp,
    float* wsm, float (*rgbL)[SS][33], float (*sigL)[SS])
{
    const int t = threadIdx.x;
    for (int i = t; i < 4257; i += 256) {
        float v;
        if (i < 2048)       v = ldv<F32>(w1b, i);
        else if (i < 2112)  v = ldv<F32>(b1b, i - 2048);
        else if (i < 4224)  v = ldv<F32>(w2b, i - 2112);
        else                v = ldv<F32>(b2b, i - 4224);
        wsm[i] = v;
    }
    __syncthreads();

    const int rl = t >> 5;
    const int s  = t & 31;
    const int gray = blockIdx.x * RPB + rl;
    const int n = gray >> 14;

    const size_t rbase = (size_t)gray * 3;
    const float ox = ldv<F32>(rayo, rbase), oy = ldv<F32>(rayo, rbase + 1), oz = ldv<F32>(rayo, rbase + 2);
    const float dx = ldv<F32>(rayd, rbase), dy = ldv<F32>(rayd, rbase + 1), dz = ldv<F32>(rayd, rbase + 2);
    const float d = 2.25f + 1.05f * ((s + 0.5f) * (1.0f / 32.0f));
    const float x = (ox + d * dx) * 2.0f;
    const float y = (oy + d * dy) * 2.0f;
    const float z = (oz + d * dz) * 2.0f;

    float fx[32];
    #pragma unroll
    for (int c = 0; c < 32; c++) fx[c] = 0.f;

    #pragma unroll
    for (int p = 0; p < 3; p++) {
        const float u = (p == 0) ? x : ((p == 1) ? y : x);
        const float v = (p == 0) ? y : z;
        const float ixf = fmaf(u, 127.5f, 127.5f);
        const float iyf = fmaf(v, 127.5f, 127.5f);
        const float ix0f = floorf(ixf), iy0f = floorf(iyf);
        const float wx1 = ixf - ix0f, wy1 = iyf - iy0f;
        const float wx0 = 1.f - wx1,  wy0 = 1.f - wy1;
        const int ix0 = iclamp((int)ix0f, 0, 255);
        const int ix1 = iclamp((int)ix0f + 1, 0, 255);
        const int iy0 = iclamp((int)iy0f, 0, 255);
        const int iy1 = iclamp((int)iy0f + 1, 0, 255);
        const float wnw = wx0 * wy0, wne = wx1 * wy0, wsw = wx0 * wy1, wse = wx1 * wy1;
        const int i00 = iy0 * WW + ix0, i01 = iy0 * WW + ix1;
        const int i10 = iy1 * WW + ix0, i11 = iy1 * WW + ix1;
        const size_t pb = (size_t)(n * 3 + p) * CC * HH * WW;
        #pragma unroll
        for (int c = 0; c < 32; c++) {
            const size_t cb = pb + (size_t)c * (HH * WW);
            fx[c] += wnw * ldv<F32>(vol, cb + i00) + wne * ldv<F32>(vol, cb + i01)
                   + wsw * ldv<F32>(vol, cb + i10) + wse * ldv<F32>(vol, cb + i11);
        }
    }
    #pragma unroll
    for (int c = 0; c < 32; c++) fx[c] *= (1.0f / 3.0f);

    const float* W1 = wsm;
    const float* B1 = wsm + 2048;
    const float* W2 = wsm + 2112;
    const float* B2 = wsm + 4224;

    float h[64];
    #pragma unroll
    for (int j = 0; j < 64; j++) h[j] = B1[j];
    #pragma unroll
    for (int c = 0; c < 32; c++) {
        const float f = fx[c];
        #pragma unroll
        for (int j = 0; j < 64; j++) h[j] = fmaf(f, W1[c * 64 + j], h[j]);
    }
    #pragma unroll
    for (int j = 0; j < 64; j++) h[j] = softplus_f(h[j]);

    #pragma unroll 1
    for (int k = 0; k < 33; k++) {
        float zz = B2[k];
        #pragma unroll
        for (int j = 0; j < 64; j++) zz = fmaf(h[j], W2[j * 33 + k], zz);
        if (k == 0) sigL[rl][s] = zz;
        else {
            const float sg = 1.0f / (1.0f + expf(-zz));
            rgbL[rl][s][k - 1] = fmaf(sg, 1.002f, -0.001f);
        }
    }
    __syncthreads();

    const int c = t & 31;
    const float delta = 1.05f / 32.0f;
    float T = 1.0f, acc = 0.0f;
    float sig_prev = sigL[rl][0];
    float rgb_prev = rgbL[rl][0][c];
    #pragma unroll 1
    for (int sm = 0; sm < 31; sm++) {
        const float sig_next = sigL[rl][sm + 1];
        const float rgb_next = rgbL[rl][sm + 1][c];
        const float dens = softplus_f(0.5f * (sig_prev + sig_next) - 1.0f);
        const float alpha = 1.0f - expf(-delta * dens);
        acc += alpha * T * 0.5f * (rgb_prev + rgb_next);
        T *= (1.0f - alpha + 1e-10f);
        sig_prev = sig_next;
        rgb_prev = rgb_next;
    }
    const size_t oidx = (size_t)gray * 32 + c;
    if (F32) ((float*)outp)[oidx] = acc;
    else     ((unsigned short*)outp)[oidx] = f2bf(acc);
}

__global__ __launch_bounds__(256) void render_any(
    const void* __restrict__ vol, const void* __restrict__ rayo,
    const void* __restrict__ rayd, const void* __restrict__ w1b,
    const void* __restrict__ b1b, const void* __restrict__ w2b,
    const void* __restrict__ b2b, void* __restrict__ outp,
    const int* __restrict__ flag)
{
    __shared__ float wsm[4257];
    __shared__ float rgbL[RPB][SS][33];
    __shared__ float sigL[RPB][SS];
    if (*flag) render_body<true >(vol, rayo, rayd, w1b, b1b, w2b, b2b, outp, wsm, rgbL, sigL);
    else       render_body<false>(vol, rayo, rayd, w1b, b1b, w2b, b2b, outp, wsm, rgbL, sigL);
}

extern "C" void kernel_launch(void* const* d_in, const int* in_sizes, int n_in,
                              void* d_out, int out_size, void* d_ws, size_t ws_size,
                              hipStream_t stream) {
    const void* vol  = d_in[0];
    const void* rayo = d_in[1];
    const void* rayd = d_in[2];
    const void* w1   = d_in[3];
    const void* b1   = d_in[4];
    const void* w2   = d_in[5];
    const void* b2   = d_in[6];
    int* flag = (int*)d_ws;
    void* tex = (void*)((char*)d_ws + TEXOFF);

    const size_t need = TEXOFF + (size_t)6 * HH * WW * CC * 4;   // f32 worst case

    detect_dtype<<<dim3(1), dim3(64), 0, stream>>>(rayo, flag);
    if (ws_size >= need) {
        transpose_tex<<<dim3(WW / 32, HH, 6), dim3(32, 32), 0, stream>>>(vol, tex, flag);
        render_fast<<<dim3(NRAYS / RPB), dim3(256), 0, stream>>>(
            tex, rayo, rayd, w1, b1, w2, b2, d_out, flag);
    } else {
        render_any<<<dim3(NRAYS / RPB), dim3(256), 0, stream>>>(
            vol, rayo, rayd, w1, b1, w2, b2, d_out, flag);
    }
}